// Round 2
// baseline (191.847 us; speedup 1.0000x reference)
//
#include <hip/hip_runtime.h>
#include <hip/hip_bf16.h>

// Problem: OptimAttn  B=32, SIZE=2048, OUT=2048 — ALL I/O float32.
// Math: valued[b,i] = sum_j exp(q_i k_j - M) v_j / Z_b,  Z_b = sum_{i,j} exp(q_i k_j - M)
// M = max of 4 corner products of (qmin,qmax)x(kmin,kmax)  (exact global max of q_i*k_j).
// Matmuls: split-bf16 MFMA (f32 = hi + lo bf16; 3 MFMAs) -> ~2^-16 relative error.

#define S 2048
#define BATCH 32

typedef __attribute__((ext_vector_type(8))) short short8;   // 8 x bf16 (MFMA A/B frag)
typedef __attribute__((ext_vector_type(4))) float f32x4;    // MFMA C/D frag

__device__ __forceinline__ float bf2f(unsigned short u) {
  union { unsigned int i; float f; } x; x.i = ((unsigned int)u) << 16; return x.f;
}
__device__ __forceinline__ unsigned short f2bf(float f) {
  union { float f; unsigned int i; } x; x.f = f;
  unsigned int r = (x.i + 0x7fffu + ((x.i >> 16) & 1u)) >> 16;
  return (unsigned short)r;
}
// f32 -> (hi, lo) bf16 pair for 8 contiguous floats (two float4 loads)
__device__ __forceinline__ void cvt8(const float* __restrict__ p, short8& hi, short8& lo) {
  const float4* p4 = (const float4*)p;
  float4 a = p4[0], b = p4[1];
  float v[8] = {a.x, a.y, a.z, a.w, b.x, b.y, b.z, b.w};
#pragma unroll
  for (int t = 0; t < 8; ++t) {
    unsigned short h = f2bf(v[t]);
    hi[t] = (short)h;
    lo[t] = (short)f2bf(v[t] - bf2f(h));
  }
}

// ---------------- K1: q,k,v = x @ W{q,k,v}.T  (split-bf16 MFMA, fp32 out) ----------------
// grid: 3 matrices * 128 n-blocks of 16.  wg=256: 4 waves split K (512 each).
// A frag: lane holds x[m=lane&15][quad*8+j]; B frag: W[n=lane&15][same k run].
// D: reg r of lane -> row = quad*4+r, col = lane&15.
__global__ __launch_bounds__(256) void k_qkv(
    const float* __restrict__ x,
    const float* __restrict__ Wq,
    const float* __restrict__ Wk,
    const float* __restrict__ Wv,
    float* __restrict__ qkv) {
  int mi   = blockIdx.x >> 7;
  int nblk = blockIdx.x & 127;
  const float* W = (mi == 0) ? Wq : (mi == 1) ? Wk : Wv;
  float* out = qkv + mi * (BATCH * S);

  int tid  = threadIdx.x;
  int wave = tid >> 6;
  int lane = tid & 63;
  int lr   = lane & 15;
  int quad = lane >> 4;

  f32x4 acc0 = {0.f, 0.f, 0.f, 0.f};
  f32x4 acc1 = {0.f, 0.f, 0.f, 0.f};
  const float* wrow = W + (size_t)(nblk * 16 + lr) * S;
  const float* xr0  = x + (size_t)lr * S;
  const float* xr1  = x + (size_t)(lr + 16) * S;
  int kbase = wave * 512 + quad * 8;

#pragma unroll 2
  for (int ks = 0; ks < 16; ++ks) {
    int k0 = kbase + ks * 32;
    short8 bhi, blo, a0h, a0l, a1h, a1l;
    cvt8(wrow + k0, bhi, blo);
    cvt8(xr0 + k0, a0h, a0l);
    cvt8(xr1 + k0, a1h, a1l);
    acc0 = __builtin_amdgcn_mfma_f32_16x16x32_bf16(a0h, bhi, acc0, 0, 0, 0);
    acc0 = __builtin_amdgcn_mfma_f32_16x16x32_bf16(a0l, bhi, acc0, 0, 0, 0);
    acc0 = __builtin_amdgcn_mfma_f32_16x16x32_bf16(a0h, blo, acc0, 0, 0, 0);
    acc1 = __builtin_amdgcn_mfma_f32_16x16x32_bf16(a1h, bhi, acc1, 0, 0, 0);
    acc1 = __builtin_amdgcn_mfma_f32_16x16x32_bf16(a1l, bhi, acc1, 0, 0, 0);
    acc1 = __builtin_amdgcn_mfma_f32_16x16x32_bf16(a1h, blo, acc1, 0, 0, 0);
  }

  __shared__ float red[4][64][8];
#pragma unroll
  for (int r = 0; r < 4; ++r) {
    red[wave][lane][r]     = acc0[r];
    red[wave][lane][4 + r] = acc1[r];
  }
  __syncthreads();
  if (tid < 64) {
    int lq = tid >> 4, lc = tid & 15;
    int n = nblk * 16 + lc;
#pragma unroll
    for (int r = 0; r < 8; ++r) {
      float s = red[0][tid][r] + red[1][tid][r] + red[2][tid][r] + red[3][tid][r];
      int m = (r < 4) ? (lq * 4 + r) : (16 + lq * 4 + (r - 4));
      out[m * S + n] = s;
    }
  }
}

// ---------------- K2: attention numerator T[b,i] and denominator Z[b] ----------------
// grid: 32 batches * 32 i-blocks of 64.  wg=256: lane = i_local, wave = j-chunk (512 j).
__global__ __launch_bounds__(256) void k_attn(
    const float* __restrict__ qkv, float* __restrict__ Tout, float* __restrict__ Z) {
  int b    = blockIdx.x >> 5;
  int iblk = blockIdx.x & 31;
  const float* q = qkv + b * S;
  const float* k = qkv + BATCH * S + b * S;
  const float* v = qkv + 2 * BATCH * S + b * S;

  __shared__ __align__(16) float2 kv[S];
  __shared__ float redmx[4][4];
  __shared__ float redST[256][2];
  __shared__ float Msh;

  int tid = threadIdx.x;
  float qmx = -1e30f, qmn = 1e30f, kmx = -1e30f, kmn = 1e30f;
  for (int idx = tid; idx < S; idx += 256) {
    float kk = k[idx], vv = v[idx], qq = q[idx];
    kv[idx] = make_float2(kk, vv);
    qmx = fmaxf(qmx, qq); qmn = fminf(qmn, qq);
    kmx = fmaxf(kmx, kk); kmn = fminf(kmn, kk);
  }
  for (int off = 32; off; off >>= 1) {
    qmx = fmaxf(qmx, __shfl_xor(qmx, off));
    qmn = fminf(qmn, __shfl_xor(qmn, off));
    kmx = fmaxf(kmx, __shfl_xor(kmx, off));
    kmn = fminf(kmn, __shfl_xor(kmn, off));
  }
  int wave = tid >> 6, lane = tid & 63;
  if (lane == 0) {
    redmx[wave][0] = qmx; redmx[wave][1] = qmn;
    redmx[wave][2] = kmx; redmx[wave][3] = kmn;
  }
  __syncthreads();
  if (tid == 0) {
    float a = redmx[0][0], bn = redmx[0][1], c = redmx[0][2], d = redmx[0][3];
    for (int w = 1; w < 4; ++w) {
      a = fmaxf(a, redmx[w][0]); bn = fminf(bn, redmx[w][1]);
      c = fmaxf(c, redmx[w][2]); d = fminf(d, redmx[w][3]);
    }
    Msh = fmaxf(fmaxf(a * c, a * d), fmaxf(bn * c, bn * d));
  }
  __syncthreads();
  float M = Msh;

  const float LOG2E = 1.4426950408889634f;
  int i = iblk * 64 + lane;
  float aa = q[i] * LOG2E;
  float cc = -M * LOG2E;
  float Sacc = 0.f, Tacc = 0.f;
  int j0 = wave * 512;
#pragma unroll 4
  for (int j = j0; j < j0 + 512; j += 2) {
    float4 p = *(const float4*)&kv[j];   // (k0,v0,k1,v1), wave-uniform addr -> broadcast
    float e0 = exp2f(fmaf(aa, p.x, cc));
    float e1 = exp2f(fmaf(aa, p.z, cc));
    Sacc += e0 + e1;
    Tacc = fmaf(e0, p.y, Tacc);
    Tacc = fmaf(e1, p.w, Tacc);
  }
  redST[tid][0] = Sacc;
  redST[tid][1] = Tacc;
  __syncthreads();
  if (tid < 64) {
    float Sf = redST[tid][0] + redST[tid + 64][0] + redST[tid + 128][0] + redST[tid + 192][0];
    float Tf = redST[tid][1] + redST[tid + 64][1] + redST[tid + 128][1] + redST[tid + 192][1];
    Tout[b * S + iblk * 64 + tid] = Tf;
    for (int off = 32; off; off >>= 1) Sf += __shfl_xor(Sf, off);
    if (tid == 0) atomicAdd(&Z[b], Sf);
  }
}

// ---------------- K2b: fc = activation(T/Z)  (fp32) ----------------
__global__ __launch_bounds__(256) void k_act(
    const float* __restrict__ Tin, const float* __restrict__ Z,
    const float* __restrict__ p2, float* __restrict__ fc) {
  int gid = blockIdx.x * 256 + threadIdx.x;   // 0..65535
  int b = gid >> 11;
  float p[5];
  float mx = -1e30f;
#pragma unroll
  for (int t = 0; t < 5; ++t) { p[t] = p2[t]; mx = fmaxf(mx, p[t]); }
  float se = 0.f;
#pragma unroll
  for (int t = 0; t < 5; ++t) { p[t] = expf(p[t] - mx); se += p[t]; }
  float inv = 1.f / se;
  float val = Tin[gid] / Z[b];
  float sig = 1.f / (1.f + expf(-val));
  fc[gid] = sig * val * (p[0] * inv) + sinf(val) * (p[1] * inv) + val * (p[2] * inv);
}

// ---------------- K3: y = fc @ Wfc2.T + bfc2  (split-bf16 MFMA, fp32 out) ----------------
__global__ __launch_bounds__(256) void k_fc(
    const float* __restrict__ fc,
    const float* __restrict__ W,
    const float* __restrict__ bias,
    float* __restrict__ y) {
  int nblk = blockIdx.x;   // 0..127
  int tid  = threadIdx.x;
  int wave = tid >> 6;
  int lane = tid & 63;
  int lr   = lane & 15;
  int quad = lane >> 4;

  f32x4 acc0 = {0.f, 0.f, 0.f, 0.f};
  f32x4 acc1 = {0.f, 0.f, 0.f, 0.f};
  const float* wrow = W + (size_t)(nblk * 16 + lr) * S;
  const float* xr0  = fc + (size_t)lr * S;
  const float* xr1  = fc + (size_t)(lr + 16) * S;
  int kbase = wave * 512 + quad * 8;

#pragma unroll 2
  for (int ks = 0; ks < 16; ++ks) {
    int k0 = kbase + ks * 32;
    short8 bhi, blo, a0h, a0l, a1h, a1l;
    cvt8(wrow + k0, bhi, blo);
    cvt8(xr0 + k0, a0h, a0l);
    cvt8(xr1 + k0, a1h, a1l);
    acc0 = __builtin_amdgcn_mfma_f32_16x16x32_bf16(a0h, bhi, acc0, 0, 0, 0);
    acc0 = __builtin_amdgcn_mfma_f32_16x16x32_bf16(a0l, bhi, acc0, 0, 0, 0);
    acc0 = __builtin_amdgcn_mfma_f32_16x16x32_bf16(a0h, blo, acc0, 0, 0, 0);
    acc1 = __builtin_amdgcn_mfma_f32_16x16x32_bf16(a1h, bhi, acc1, 0, 0, 0);
    acc1 = __builtin_amdgcn_mfma_f32_16x16x32_bf16(a1l, bhi, acc1, 0, 0, 0);
    acc1 = __builtin_amdgcn_mfma_f32_16x16x32_bf16(a1h, blo, acc1, 0, 0, 0);
  }

  __shared__ float red[4][64][8];
#pragma unroll
  for (int r = 0; r < 4; ++r) {
    red[wave][lane][r]     = acc0[r];
    red[wave][lane][4 + r] = acc1[r];
  }
  __syncthreads();
  if (tid < 64) {
    int lq = tid >> 4, lc = tid & 15;
    int n = nblk * 16 + lc;
    float bsum = bias[n];
#pragma unroll
    for (int r = 0; r < 8; ++r) {
      float s = red[0][tid][r] + red[1][tid][r] + red[2][tid][r] + red[3][tid][r];
      int m = (r < 4) ? (lq * 4 + r) : (16 + lq * 4 + (r - 4));
      y[m * S + n] = s + bsum;
    }
  }
}

// ---------------- K4: layernorm -> fp32 output ----------------
__global__ __launch_bounds__(256) void k_ln(
    const float* __restrict__ y, const float* __restrict__ g,
    const float* __restrict__ bb, float* __restrict__ out) {
  int b = blockIdx.x;
  const float* row = y + b * S;
  float s = 0.f, s2 = 0.f;
  for (int i = threadIdx.x; i < S; i += 256) {
    float t = row[i];
    s += t; s2 += t * t;
  }
  for (int off = 32; off; off >>= 1) {
    s  += __shfl_xor(s, off);
    s2 += __shfl_xor(s2, off);
  }
  __shared__ float rs[4], rs2[4];
  __shared__ float mu_s, r_s;
  int wave = threadIdx.x >> 6, lane = threadIdx.x & 63;
  if (lane == 0) { rs[wave] = s; rs2[wave] = s2; }
  __syncthreads();
  if (threadIdx.x == 0) {
    float S1 = rs[0] + rs[1] + rs[2] + rs[3];
    float S2 = rs2[0] + rs2[1] + rs2[2] + rs2[3];
    float mu = S1 / (float)S;
    float var = S2 / (float)S - mu * mu;
    mu_s = mu;
    r_s = rsqrtf(var + 1e-5f);
  }
  __syncthreads();
  float mu = mu_s, r = r_s;
  for (int i = threadIdx.x; i < S; i += 256) {
    out[b * S + i] = (row[i] - mu) * r * g[i] + bb[i];
  }
}

extern "C" void kernel_launch(void* const* d_in, const int* in_sizes, int n_in,
                              void* d_out, int out_size, void* d_ws, size_t ws_size,
                              hipStream_t stream) {
  (void)in_sizes; (void)n_in; (void)out_size; (void)ws_size;
  const float* x    = (const float*)d_in[0];
  const float* Wq   = (const float*)d_in[1];
  const float* Wk   = (const float*)d_in[2];
  const float* Wv   = (const float*)d_in[3];
  const float* p2   = (const float*)d_in[4];
  const float* Wfc2 = (const float*)d_in[5];
  const float* bfc2 = (const float*)d_in[6];
  const float* g2   = (const float*)d_in[7];
  const float* b2   = (const float*)d_in[8];
  float* out = (float*)d_out;

  float* qkv = (float*)d_ws;                 // 3 * 32*2048 f32
  float* T   = qkv + 3 * BATCH * S;          // 32*2048 f32
  float* Z   = T + BATCH * S;                // 32 f32
  float* fc  = Z + 32;                       // 32*2048 f32
  float* y   = fc + BATCH * S;               // 32*2048 f32

  hipMemsetAsync(Z, 0, 32 * sizeof(float), stream);
  k_qkv<<<384, 256, 0, stream>>>(x, Wq, Wk, Wv, qkv);
  k_attn<<<1024, 256, 0, stream>>>(qkv, T, Z);
  k_act<<<256, 256, 0, stream>>>(T, Z, p2, fc);
  k_fc<<<128, 256, 0, stream>>>(fc, Wfc2, bfc2, y);
  k_ln<<<32, 256, 0, stream>>>(y, g2, b2, out);
}

// Round 3
// 171.107 us; speedup vs baseline: 1.1212x; 1.1212x over previous
//
#include <hip/hip_runtime.h>
#include <hip/hip_bf16.h>

// Problem: OptimAttn  B=32, SIZE=2048, OUT=2048 — ALL I/O float32.
// valued[b,i] = sum_j exp(q_i k_j - M) v_j / Z_b,  Z_b = sum_{i,j} exp(q_i k_j - M)
// M = max of 4 corner products of (qmin,qmax)x(kmin,kmax)  (exact global max).
// Matmuls: truncation-split bf16 MFMA (f32 = hi + lo; 3 MFMAs) -> ~2^-16 rel error.
// Round 3: bare v_exp_f32 in attention; cheap truncation split; wg=512 K-split GEMMs.

#define S 2048
#define BATCH 32

typedef __attribute__((ext_vector_type(8))) short short8;   // 8 x bf16 (MFMA A/B frag)
typedef __attribute__((ext_vector_type(4))) float f32x4;    // MFMA C/D frag

// Truncation-based f32 -> (hi,lo) bf16 split, 4 VALU/elem.
// hi = trunc16(f); lo = trunc16(f - hi)  (f - hi is exact; total rel err ~2^-16)
__device__ __forceinline__ void cvt8t(const float* __restrict__ p, short8& hi, short8& lo) {
  const float4* p4 = (const float4*)p;
  float4 a = p4[0], b = p4[1];
  float v[8] = {a.x, a.y, a.z, a.w, b.x, b.y, b.z, b.w};
#pragma unroll
  for (int t = 0; t < 8; ++t) {
    union { float f; unsigned u; } x; x.f = v[t];
    unsigned hb = x.u & 0xFFFF0000u;
    hi[t] = (short)(x.u >> 16);
    union { unsigned u; float f; } h; h.u = hb;
    union { float f; unsigned u; } l; l.f = v[t] - h.f;
    lo[t] = (short)(l.u >> 16);
  }
}

// ---------------- K1: q,k,v = x @ W{q,k,v}.T  (split-bf16 MFMA, fp32 out) ----------------
// grid: 3 * 128 n-blocks.  wg=512: 8 waves split K (256 each) -> more latency hiding.
__global__ __launch_bounds__(512) void k_qkv(
    const float* __restrict__ x,
    const float* __restrict__ Wq,
    const float* __restrict__ Wk,
    const float* __restrict__ Wv,
    float* __restrict__ qkv) {
  int mi   = blockIdx.x >> 7;
  int nblk = blockIdx.x & 127;
  const float* W = (mi == 0) ? Wq : (mi == 1) ? Wk : Wv;
  float* out = qkv + mi * (BATCH * S);

  int tid  = threadIdx.x;
  int wave = tid >> 6;
  int lane = tid & 63;
  int lr   = lane & 15;
  int quad = lane >> 4;

  f32x4 acc0 = {0.f, 0.f, 0.f, 0.f};
  f32x4 acc1 = {0.f, 0.f, 0.f, 0.f};
  const float* wrow = W + (size_t)(nblk * 16 + lr) * S;
  const float* xr0  = x + (size_t)lr * S;
  const float* xr1  = x + (size_t)(lr + 16) * S;
  int kbase = wave * 256 + quad * 8;

#pragma unroll 2
  for (int ks = 0; ks < 8; ++ks) {
    int k0 = kbase + ks * 32;
    short8 bhi, blo, a0h, a0l, a1h, a1l;
    cvt8t(wrow + k0, bhi, blo);
    cvt8t(xr0 + k0, a0h, a0l);
    cvt8t(xr1 + k0, a1h, a1l);
    acc0 = __builtin_amdgcn_mfma_f32_16x16x32_bf16(a0h, bhi, acc0, 0, 0, 0);
    acc0 = __builtin_amdgcn_mfma_f32_16x16x32_bf16(a0l, bhi, acc0, 0, 0, 0);
    acc0 = __builtin_amdgcn_mfma_f32_16x16x32_bf16(a0h, blo, acc0, 0, 0, 0);
    acc1 = __builtin_amdgcn_mfma_f32_16x16x32_bf16(a1h, bhi, acc1, 0, 0, 0);
    acc1 = __builtin_amdgcn_mfma_f32_16x16x32_bf16(a1l, bhi, acc1, 0, 0, 0);
    acc1 = __builtin_amdgcn_mfma_f32_16x16x32_bf16(a1h, blo, acc1, 0, 0, 0);
  }

  __shared__ float red[8][64][8];
#pragma unroll
  for (int r = 0; r < 4; ++r) {
    red[wave][lane][r]     = acc0[r];
    red[wave][lane][4 + r] = acc1[r];
  }
  __syncthreads();
  if (tid < 64) {
    int lq = tid >> 4, lc = tid & 15;
    int n = nblk * 16 + lc;
#pragma unroll
    for (int r = 0; r < 8; ++r) {
      float s = 0.f;
#pragma unroll
      for (int w = 0; w < 8; ++w) s += red[w][tid][r];
      int m = (r < 4) ? (lq * 4 + r) : (16 + lq * 4 + (r - 4));
      out[m * S + n] = s;
    }
  }
}

// ---------------- K2: attention numerator T[b,i] and denominator Z[b] ----------------
// grid: 32 batches * 32 i-blocks of 64.  wg=256: lane = i_local, wave = j-chunk (512 j).
__global__ __launch_bounds__(256) void k_attn(
    const float* __restrict__ qkv, float* __restrict__ Tout, float* __restrict__ Z) {
  int b    = blockIdx.x >> 5;
  int iblk = blockIdx.x & 31;
  const float* q = qkv + b * S;
  const float* k = qkv + BATCH * S + b * S;
  const float* v = qkv + 2 * BATCH * S + b * S;

  __shared__ __align__(16) float2 kv[S];
  __shared__ float redmx[4][4];
  __shared__ float redST[256][2];
  __shared__ float Msh;

  int tid = threadIdx.x;
  float qmx = -1e30f, qmn = 1e30f, kmx = -1e30f, kmn = 1e30f;
  for (int idx = tid; idx < S; idx += 256) {
    float kk = k[idx], vv = v[idx], qq = q[idx];
    kv[idx] = make_float2(kk, vv);
    qmx = fmaxf(qmx, qq); qmn = fminf(qmn, qq);
    kmx = fmaxf(kmx, kk); kmn = fminf(kmn, kk);
  }
  for (int off = 32; off; off >>= 1) {
    qmx = fmaxf(qmx, __shfl_xor(qmx, off));
    qmn = fminf(qmn, __shfl_xor(qmn, off));
    kmx = fmaxf(kmx, __shfl_xor(kmx, off));
    kmn = fminf(kmn, __shfl_xor(kmn, off));
  }
  int wave = tid >> 6, lane = tid & 63;
  if (lane == 0) {
    redmx[wave][0] = qmx; redmx[wave][1] = qmn;
    redmx[wave][2] = kmx; redmx[wave][3] = kmn;
  }
  __syncthreads();
  if (tid == 0) {
    float a = redmx[0][0], bn = redmx[0][1], c = redmx[0][2], d = redmx[0][3];
    for (int w = 1; w < 4; ++w) {
      a = fmaxf(a, redmx[w][0]); bn = fminf(bn, redmx[w][1]);
      c = fmaxf(c, redmx[w][2]); d = fminf(d, redmx[w][3]);
    }
    Msh = fmaxf(fmaxf(a * c, a * d), fmaxf(bn * c, bn * d));
  }
  __syncthreads();
  float M = Msh;

  const float LOG2E = 1.4426950408889634f;
  int i = iblk * 64 + lane;
  float aa = q[i] * LOG2E;
  float cc = -M * LOG2E;
  float Sacc = 0.f, Tacc = 0.f;
  int j0 = wave * 512;
#pragma unroll 8
  for (int j = j0; j < j0 + 512; j += 2) {
    float4 p = *(const float4*)&kv[j];   // (k0,v0,k1,v1), wave-uniform addr -> broadcast
    float e0 = __builtin_amdgcn_exp2f(fmaf(aa, p.x, cc));  // bare v_exp_f32, arg <= 0
    float e1 = __builtin_amdgcn_exp2f(fmaf(aa, p.z, cc));
    Sacc += e0 + e1;
    Tacc = fmaf(e0, p.y, fmaf(e1, p.w, Tacc));
  }
  redST[tid][0] = Sacc;
  redST[tid][1] = Tacc;
  __syncthreads();
  if (tid < 64) {
    float Sf = redST[tid][0] + redST[tid + 64][0] + redST[tid + 128][0] + redST[tid + 192][0];
    float Tf = redST[tid][1] + redST[tid + 64][1] + redST[tid + 128][1] + redST[tid + 192][1];
    Tout[b * S + iblk * 64 + tid] = Tf;
    for (int off = 32; off; off >>= 1) Sf += __shfl_xor(Sf, off);
    if (tid == 0) atomicAdd(&Z[b], Sf);
  }
}

// ---------------- K2b: fc = activation(T/Z)  (fp32) ----------------
__global__ __launch_bounds__(256) void k_act(
    const float* __restrict__ Tin, const float* __restrict__ Z,
    const float* __restrict__ p2, float* __restrict__ fc) {
  int gid = blockIdx.x * 256 + threadIdx.x;   // 0..65535
  int b = gid >> 11;
  const float LOG2E = 1.4426950408889634f;
  float p[5];
  float mx = -1e30f;
#pragma unroll
  for (int t = 0; t < 5; ++t) { p[t] = p2[t]; mx = fmaxf(mx, p[t]); }
  float se = 0.f;
#pragma unroll
  for (int t = 0; t < 5; ++t) { p[t] = __builtin_amdgcn_exp2f((p[t] - mx) * LOG2E); se += p[t]; }
  float inv = 1.f / se;
  float val = Tin[gid] / Z[b];
  float sig = __builtin_amdgcn_rcpf(1.f + __builtin_amdgcn_exp2f(-val * LOG2E));
  float sn  = __builtin_amdgcn_sinf(val * 0.15915494309189535f);  // v_sin takes revolutions
  fc[gid] = sig * val * (p[0] * inv) + sn * (p[1] * inv) + val * (p[2] * inv);
}

// ---------------- K3: y = fc @ Wfc2.T + bfc2  (split-bf16 MFMA, fp32 out) ----------------
__global__ __launch_bounds__(512) void k_fc(
    const float* __restrict__ fc,
    const float* __restrict__ W,
    const float* __restrict__ bias,
    float* __restrict__ y) {
  int nblk = blockIdx.x;   // 0..127
  int tid  = threadIdx.x;
  int wave = tid >> 6;
  int lane = tid & 63;
  int lr   = lane & 15;
  int quad = lane >> 4;

  f32x4 acc0 = {0.f, 0.f, 0.f, 0.f};
  f32x4 acc1 = {0.f, 0.f, 0.f, 0.f};
  const float* wrow = W + (size_t)(nblk * 16 + lr) * S;
  const float* xr0  = fc + (size_t)lr * S;
  const float* xr1  = fc + (size_t)(lr + 16) * S;
  int kbase = wave * 256 + quad * 8;

#pragma unroll 2
  for (int ks = 0; ks < 8; ++ks) {
    int k0 = kbase + ks * 32;
    short8 bhi, blo, a0h, a0l, a1h, a1l;
    cvt8t(wrow + k0, bhi, blo);
    cvt8t(xr0 + k0, a0h, a0l);
    cvt8t(xr1 + k0, a1h, a1l);
    acc0 = __builtin_amdgcn_mfma_f32_16x16x32_bf16(a0h, bhi, acc0, 0, 0, 0);
    acc0 = __builtin_amdgcn_mfma_f32_16x16x32_bf16(a0l, bhi, acc0, 0, 0, 0);
    acc0 = __builtin_amdgcn_mfma_f32_16x16x32_bf16(a0h, blo, acc0, 0, 0, 0);
    acc1 = __builtin_amdgcn_mfma_f32_16x16x32_bf16(a1h, bhi, acc1, 0, 0, 0);
    acc1 = __builtin_amdgcn_mfma_f32_16x16x32_bf16(a1l, bhi, acc1, 0, 0, 0);
    acc1 = __builtin_amdgcn_mfma_f32_16x16x32_bf16(a1h, blo, acc1, 0, 0, 0);
  }

  __shared__ float red[8][64][8];
#pragma unroll
  for (int r = 0; r < 4; ++r) {
    red[wave][lane][r]     = acc0[r];
    red[wave][lane][4 + r] = acc1[r];
  }
  __syncthreads();
  if (tid < 64) {
    int lq = tid >> 4, lc = tid & 15;
    int n = nblk * 16 + lc;
    float bsum = bias[n];
#pragma unroll
    for (int r = 0; r < 8; ++r) {
      float s = 0.f;
#pragma unroll
      for (int w = 0; w < 8; ++w) s += red[w][tid][r];
      int m = (r < 4) ? (lq * 4 + r) : (16 + lq * 4 + (r - 4));
      y[m * S + n] = s + bsum;
    }
  }
}

// ---------------- K4: layernorm -> fp32 output ----------------
__global__ __launch_bounds__(256) void k_ln(
    const float* __restrict__ y, const float* __restrict__ g,
    const float* __restrict__ bb, float* __restrict__ out) {
  int b = blockIdx.x;
  const float* row = y + b * S;
  float s = 0.f, s2 = 0.f;
  for (int i = threadIdx.x; i < S; i += 256) {
    float t = row[i];
    s += t; s2 += t * t;
  }
  for (int off = 32; off; off >>= 1) {
    s  += __shfl_xor(s, off);
    s2 += __shfl_xor(s2, off);
  }
  __shared__ float rs[4], rs2[4];
  __shared__ float mu_s, r_s;
  int wave = threadIdx.x >> 6, lane = threadIdx.x & 63;
  if (lane == 0) { rs[wave] = s; rs2[wave] = s2; }
  __syncthreads();
  if (threadIdx.x == 0) {
    float S1 = rs[0] + rs[1] + rs[2] + rs[3];
    float S2 = rs2[0] + rs2[1] + rs2[2] + rs2[3];
    float mu = S1 / (float)S;
    float var = S2 / (float)S - mu * mu;
    mu_s = mu;
    r_s = rsqrtf(var + 1e-5f);
  }
  __syncthreads();
  float mu = mu_s, r = r_s;
  for (int i = threadIdx.x; i < S; i += 256) {
    out[b * S + i] = (row[i] - mu) * r * g[i] + bb[i];
  }
}

extern "C" void kernel_launch(void* const* d_in, const int* in_sizes, int n_in,
                              void* d_out, int out_size, void* d_ws, size_t ws_size,
                              hipStream_t stream) {
  (void)in_sizes; (void)n_in; (void)out_size; (void)ws_size;
  const float* x    = (const float*)d_in[0];
  const float* Wq   = (const float*)d_in[1];
  const float* Wk   = (const float*)d_in[2];
  const float* Wv   = (const float*)d_in[3];
  const float* p2   = (const float*)d_in[4];
  const float* Wfc2 = (const float*)d_in[5];
  const float* bfc2 = (const float*)d_in[6];
  const float* g2   = (const float*)d_in[7];
  const float* b2   = (const float*)d_in[8];
  float* out = (float*)d_out;

  float* qkv = (float*)d_ws;                 // 3 * 32*2048 f32
  float* T   = qkv + 3 * BATCH * S;          // 32*2048 f32
  float* Z   = T + BATCH * S;                // 32 f32
  float* fc  = Z + 32;                       // 32*2048 f32
  float* y   = fc + BATCH * S;               // 32*2048 f32

  hipMemsetAsync(Z, 0, 32 * sizeof(float), stream);
  k_qkv<<<384, 512, 0, stream>>>(x, Wq, Wk, Wv, qkv);
  k_attn<<<1024, 256, 0, stream>>>(qkv, T, Z);
  k_act<<<256, 256, 0, stream>>>(T, Z, p2, fc);
  k_fc<<<128, 512, 0, stream>>>(fc, Wfc2, bfc2, y);
  k_ln<<<32, 256, 0, stream>>>(y, g2, b2, out);
}

// Round 4
// 152.721 us; speedup vs baseline: 1.2562x; 1.1204x over previous
//
#include <hip/hip_runtime.h>
#include <hip/hip_bf16.h>

// Problem: OptimAttn  B=32, SIZE=2048, OUT=2048 — ALL I/O float32.
// valued[b,i] = sum_j exp(q_i k_j - M) v_j / Z_b,  Z_b = sum_{i,j} exp(q_i k_j - M)
// M = max of 4 corner products of (qmin,qmax)x(kmin,kmax)  (exact global max).
// Matmuls: truncation-split bf16 MFMA (f32 = hi + lo; 3 MFMAs) -> ~2^-16 rel error.
// Round 4: split-K across blocks for k_qkv (768 blk) and k_fc (256 blk) to fix
// CU load imbalance; no atomics/memset (per-block partials, reduced downstream).

#define S 2048
#define BATCH 32

typedef __attribute__((ext_vector_type(8))) short short8;   // 8 x bf16 (MFMA A/B frag)
typedef __attribute__((ext_vector_type(4))) float f32x4;    // MFMA C/D frag

// Truncation-based f32 -> (hi,lo) bf16 split, ~4 VALU/elem.
__device__ __forceinline__ void cvt8t(const float* __restrict__ p, short8& hi, short8& lo) {
  const float4* p4 = (const float4*)p;
  float4 a = p4[0], b = p4[1];
  float v[8] = {a.x, a.y, a.z, a.w, b.x, b.y, b.z, b.w};
#pragma unroll
  for (int t = 0; t < 8; ++t) {
    union { float f; unsigned u; } x; x.f = v[t];
    hi[t] = (short)(x.u >> 16);
    union { unsigned u; float f; } h; h.u = x.u & 0xFFFF0000u;
    union { float f; unsigned u; } l; l.f = v[t] - h.f;
    lo[t] = (short)(l.u >> 16);
  }
}

// ---------------- K1: qkv partials = x @ W{q,k,v}.T over K-half ----------------
// grid: 768 = mi(3) x kh(2) x nblk(128).  wg=256: 4 waves x 256 K each.
__global__ __launch_bounds__(256) void k_qkv(
    const float* __restrict__ x,
    const float* __restrict__ Wq,
    const float* __restrict__ Wk,
    const float* __restrict__ Wv,
    float* __restrict__ qkvp) {
  int bid  = blockIdx.x;
  int mi   = bid >> 8;          // 0..2
  int kh   = (bid >> 7) & 1;    // K half
  int nblk = bid & 127;
  const float* W = (mi == 0) ? Wq : (mi == 1) ? Wk : Wv;
  float* out = qkvp + (size_t)kh * (3 * BATCH * S) + (size_t)mi * (BATCH * S);

  int tid  = threadIdx.x;
  int wave = tid >> 6;
  int lane = tid & 63;
  int lr   = lane & 15;
  int quad = lane >> 4;

  f32x4 acc0 = {0.f, 0.f, 0.f, 0.f};
  f32x4 acc1 = {0.f, 0.f, 0.f, 0.f};
  const float* wrow = W + (size_t)(nblk * 16 + lr) * S;
  const float* xr0  = x + (size_t)lr * S;
  const float* xr1  = x + (size_t)(lr + 16) * S;
  int kbase = kh * 1024 + wave * 256 + quad * 8;

#pragma unroll 2
  for (int ks = 0; ks < 8; ++ks) {
    int k0 = kbase + ks * 32;
    short8 bhi, blo, a0h, a0l, a1h, a1l;
    cvt8t(wrow + k0, bhi, blo);
    cvt8t(xr0 + k0, a0h, a0l);
    cvt8t(xr1 + k0, a1h, a1l);
    acc0 = __builtin_amdgcn_mfma_f32_16x16x32_bf16(a0h, bhi, acc0, 0, 0, 0);
    acc0 = __builtin_amdgcn_mfma_f32_16x16x32_bf16(a0l, bhi, acc0, 0, 0, 0);
    acc0 = __builtin_amdgcn_mfma_f32_16x16x32_bf16(a0h, blo, acc0, 0, 0, 0);
    acc1 = __builtin_amdgcn_mfma_f32_16x16x32_bf16(a1h, bhi, acc1, 0, 0, 0);
    acc1 = __builtin_amdgcn_mfma_f32_16x16x32_bf16(a1l, bhi, acc1, 0, 0, 0);
    acc1 = __builtin_amdgcn_mfma_f32_16x16x32_bf16(a1h, blo, acc1, 0, 0, 0);
  }

  __shared__ float red[4][64][8];
#pragma unroll
  for (int r = 0; r < 4; ++r) {
    red[wave][lane][r]     = acc0[r];
    red[wave][lane][4 + r] = acc1[r];
  }
  __syncthreads();
  if (tid < 64) {
    int lq = tid >> 4, lc = tid & 15;
    int n = nblk * 16 + lc;
#pragma unroll
    for (int r = 0; r < 8; ++r) {
      float s = red[0][tid][r] + red[1][tid][r] + red[2][tid][r] + red[3][tid][r];
      int m = (r < 4) ? (lq * 4 + r) : (16 + lq * 4 + (r - 4));
      out[m * S + n] = s;
    }
  }
}

// ---------------- K2: attention numerator T[b,i] and partial sums Spart ----------------
// grid: 32 batches * 32 i-blocks of 64.  wg=256: lane = i_local, wave = j-chunk (512 j).
__global__ __launch_bounds__(256) void k_attn(
    const float* __restrict__ qkvp, float* __restrict__ Tout, float* __restrict__ Spart) {
  int b    = blockIdx.x >> 5;
  int iblk = blockIdx.x & 31;
  const float* qA = qkvp + (size_t)b * S;
  const float* kA = qA + BATCH * S;
  const float* vA = qA + 2 * BATCH * S;
  const float* qB = qA + 3 * BATCH * S;
  const float* kB = kA + 3 * BATCH * S;
  const float* vB = vA + 3 * BATCH * S;

  __shared__ __align__(16) float2 kv[S];
  __shared__ float qsh[64];
  __shared__ float redmx[4][4];
  __shared__ float redST[256][2];
  __shared__ float Msh;

  int tid = threadIdx.x;
  float qmx = -1e30f, qmn = 1e30f, kmx = -1e30f, kmn = 1e30f;
  for (int idx = tid; idx < S; idx += 256) {
    float kk = kA[idx] + kB[idx];
    float vv = vA[idx] + vB[idx];
    float qq = qA[idx] + qB[idx];
    kv[idx] = make_float2(kk, vv);
    if ((idx >> 6) == iblk) qsh[idx & 63] = qq;
    qmx = fmaxf(qmx, qq); qmn = fminf(qmn, qq);
    kmx = fmaxf(kmx, kk); kmn = fminf(kmn, kk);
  }
  for (int off = 32; off; off >>= 1) {
    qmx = fmaxf(qmx, __shfl_xor(qmx, off));
    qmn = fminf(qmn, __shfl_xor(qmn, off));
    kmx = fmaxf(kmx, __shfl_xor(kmx, off));
    kmn = fminf(kmn, __shfl_xor(kmn, off));
  }
  int wave = tid >> 6, lane = tid & 63;
  if (lane == 0) {
    redmx[wave][0] = qmx; redmx[wave][1] = qmn;
    redmx[wave][2] = kmx; redmx[wave][3] = kmn;
  }
  __syncthreads();
  if (tid == 0) {
    float a = redmx[0][0], bn = redmx[0][1], c = redmx[0][2], d = redmx[0][3];
    for (int w = 1; w < 4; ++w) {
      a = fmaxf(a, redmx[w][0]); bn = fminf(bn, redmx[w][1]);
      c = fmaxf(c, redmx[w][2]); d = fminf(d, redmx[w][3]);
    }
    Msh = fmaxf(fmaxf(a * c, a * d), fmaxf(bn * c, bn * d));
  }
  __syncthreads();
  float M = Msh;

  const float LOG2E = 1.4426950408889634f;
  float aa = qsh[lane] * LOG2E;
  float cc = -M * LOG2E;
  float S0 = 0.f, S1 = 0.f, T0 = 0.f, T1 = 0.f;
  int j0 = wave * 512;
#pragma unroll 4
  for (int j = j0; j < j0 + 512; j += 4) {
    float4 p0 = *(const float4*)&kv[j];       // (k0,v0,k1,v1) wave-uniform -> broadcast
    float4 p1 = *(const float4*)&kv[j + 2];   // (k2,v2,k3,v3)
    float e0 = __builtin_amdgcn_exp2f(fmaf(aa, p0.x, cc));
    float e1 = __builtin_amdgcn_exp2f(fmaf(aa, p0.z, cc));
    float e2 = __builtin_amdgcn_exp2f(fmaf(aa, p1.x, cc));
    float e3 = __builtin_amdgcn_exp2f(fmaf(aa, p1.z, cc));
    S0 += e0 + e1;
    S1 += e2 + e3;
    T0 = fmaf(e0, p0.y, fmaf(e1, p0.w, T0));
    T1 = fmaf(e2, p1.y, fmaf(e3, p1.w, T1));
  }
  redST[tid][0] = S0 + S1;
  redST[tid][1] = T0 + T1;
  __syncthreads();
  if (tid < 64) {
    float Sf = redST[tid][0] + redST[tid + 64][0] + redST[tid + 128][0] + redST[tid + 192][0];
    float Tf = redST[tid][1] + redST[tid + 64][1] + redST[tid + 128][1] + redST[tid + 192][1];
    Tout[b * S + iblk * 64 + tid] = Tf;
    for (int off = 32; off; off >>= 1) Sf += __shfl_xor(Sf, off);
    if (tid == 0) Spart[b * 32 + iblk] = Sf;
  }
}

// ---------------- K2b: fc = activation(T/Z)  (fp32); Z from 32 partials ----------------
__global__ __launch_bounds__(256) void k_act(
    const float* __restrict__ Tin, const float* __restrict__ Spart,
    const float* __restrict__ p2, float* __restrict__ fc) {
  int tid = threadIdx.x;
  int gid = blockIdx.x * 256 + tid;   // 0..65535
  int b = gid >> 11;                  // uniform per block (2048 per b, 8 blocks/b)
  __shared__ float Zsh;
  if (tid < 64) {
    float zv = (tid < 32) ? Spart[b * 32 + tid] : 0.f;
    for (int off = 32; off; off >>= 1) zv += __shfl_xor(zv, off);
    if (tid == 0) Zsh = zv;
  }
  __syncthreads();
  float Z = Zsh;

  const float LOG2E = 1.4426950408889634f;
  float p[5];
  float mx = -1e30f;
#pragma unroll
  for (int t = 0; t < 5; ++t) { p[t] = p2[t]; mx = fmaxf(mx, p[t]); }
  float se = 0.f;
#pragma unroll
  for (int t = 0; t < 5; ++t) { p[t] = __builtin_amdgcn_exp2f((p[t] - mx) * LOG2E); se += p[t]; }
  float inv = 1.f / se;
  float val = Tin[gid] / Z;
  float sig = __builtin_amdgcn_rcpf(1.f + __builtin_amdgcn_exp2f(-val * LOG2E));
  float sn  = __builtin_amdgcn_sinf(val * 0.15915494309189535f);  // v_sin takes revolutions
  fc[gid] = sig * val * (p[0] * inv) + sn * (p[1] * inv) + val * (p[2] * inv);
}

// ---------------- K3: y partials = fc @ Wfc2.T over K-half (no bias) ----------------
// grid: 256 = kh(2) x nblk(128).  wg=512: 8 waves x 128 K each.
__global__ __launch_bounds__(512) void k_fc(
    const float* __restrict__ fc,
    const float* __restrict__ W,
    float* __restrict__ yp) {
  int bid  = blockIdx.x;
  int kh   = bid >> 7;
  int nblk = bid & 127;
  int tid  = threadIdx.x;
  int wave = tid >> 6;
  int lane = tid & 63;
  int lr   = lane & 15;
  int quad = lane >> 4;

  f32x4 acc0 = {0.f, 0.f, 0.f, 0.f};
  f32x4 acc1 = {0.f, 0.f, 0.f, 0.f};
  const float* wrow = W + (size_t)(nblk * 16 + lr) * S;
  const float* xr0  = fc + (size_t)lr * S;
  const float* xr1  = fc + (size_t)(lr + 16) * S;
  int kbase = kh * 1024 + wave * 128 + quad * 8;

#pragma unroll
  for (int ks = 0; ks < 4; ++ks) {
    int k0 = kbase + ks * 32;
    short8 bhi, blo, a0h, a0l, a1h, a1l;
    cvt8t(wrow + k0, bhi, blo);
    cvt8t(xr0 + k0, a0h, a0l);
    cvt8t(xr1 + k0, a1h, a1l);
    acc0 = __builtin_amdgcn_mfma_f32_16x16x32_bf16(a0h, bhi, acc0, 0, 0, 0);
    acc0 = __builtin_amdgcn_mfma_f32_16x16x32_bf16(a0l, bhi, acc0, 0, 0, 0);
    acc0 = __builtin_amdgcn_mfma_f32_16x16x32_bf16(a0h, blo, acc0, 0, 0, 0);
    acc1 = __builtin_amdgcn_mfma_f32_16x16x32_bf16(a1h, bhi, acc1, 0, 0, 0);
    acc1 = __builtin_amdgcn_mfma_f32_16x16x32_bf16(a1l, bhi, acc1, 0, 0, 0);
    acc1 = __builtin_amdgcn_mfma_f32_16x16x32_bf16(a1h, blo, acc1, 0, 0, 0);
  }

  __shared__ float red[8][64][8];
#pragma unroll
  for (int r = 0; r < 4; ++r) {
    red[wave][lane][r]     = acc0[r];
    red[wave][lane][4 + r] = acc1[r];
  }
  __syncthreads();
  if (tid < 64) {
    int lq = tid >> 4, lc = tid & 15;
    int n = nblk * 16 + lc;
#pragma unroll
    for (int r = 0; r < 8; ++r) {
      float s = 0.f;
#pragma unroll
      for (int w = 0; w < 8; ++w) s += red[w][tid][r];
      int m = (r < 4) ? (lq * 4 + r) : (16 + lq * 4 + (r - 4));
      yp[(size_t)kh * BATCH * S + m * S + n] = s;
    }
  }
}

// ---------------- K4: layernorm(y0+y1+bias) -> fp32 output ----------------
__global__ __launch_bounds__(256) void k_ln(
    const float* __restrict__ yp, const float* __restrict__ bias,
    const float* __restrict__ g, const float* __restrict__ bb,
    float* __restrict__ out) {
  int b = blockIdx.x;
  const float* r0 = yp + (size_t)b * S;
  const float* r1 = r0 + BATCH * S;
  float t8[8];
  float s = 0.f, s2 = 0.f;
#pragma unroll
  for (int it = 0; it < 8; ++it) {
    int i = threadIdx.x + it * 256;
    float t = r0[i] + r1[i] + bias[i];
    t8[it] = t;
    s += t; s2 += t * t;
  }
  for (int off = 32; off; off >>= 1) {
    s  += __shfl_xor(s, off);
    s2 += __shfl_xor(s2, off);
  }
  __shared__ float rs[4], rs2[4];
  __shared__ float mu_s, r_s;
  int wave = threadIdx.x >> 6, lane = threadIdx.x & 63;
  if (lane == 0) { rs[wave] = s; rs2[wave] = s2; }
  __syncthreads();
  if (threadIdx.x == 0) {
    float S1 = rs[0] + rs[1] + rs[2] + rs[3];
    float S2 = rs2[0] + rs2[1] + rs2[2] + rs2[3];
    float mu = S1 / (float)S;
    float var = S2 / (float)S - mu * mu;
    mu_s = mu;
    r_s = rsqrtf(var + 1e-5f);
  }
  __syncthreads();
  float mu = mu_s, r = r_s;
#pragma unroll
  for (int it = 0; it < 8; ++it) {
    int i = threadIdx.x + it * 256;
    out[b * S + i] = (t8[it] - mu) * r * g[i] + bb[i];
  }
}

extern "C" void kernel_launch(void* const* d_in, const int* in_sizes, int n_in,
                              void* d_out, int out_size, void* d_ws, size_t ws_size,
                              hipStream_t stream) {
  (void)in_sizes; (void)n_in; (void)out_size; (void)ws_size;
  const float* x    = (const float*)d_in[0];
  const float* Wq   = (const float*)d_in[1];
  const float* Wk   = (const float*)d_in[2];
  const float* Wv   = (const float*)d_in[3];
  const float* p2   = (const float*)d_in[4];
  const float* Wfc2 = (const float*)d_in[5];
  const float* bfc2 = (const float*)d_in[6];
  const float* g2   = (const float*)d_in[7];
  const float* b2   = (const float*)d_in[8];
  float* out = (float*)d_out;

  float* qkvp  = (float*)d_ws;                    // 2 * 3*32*2048 f32
  float* T     = qkvp + 2 * 3 * BATCH * S;        // 32*2048 f32
  float* Spart = T + BATCH * S;                   // 32*32 f32
  float* fc    = Spart + BATCH * 32;              // 32*2048 f32
  float* yp    = fc + BATCH * S;                  // 2 * 32*2048 f32

  k_qkv<<<768, 256, 0, stream>>>(x, Wq, Wk, Wv, qkvp);
  k_attn<<<1024, 256, 0, stream>>>(qkvp, T, Spart);
  k_act<<<256, 256, 0, stream>>>(T, Spart, p2, fc);
  k_fc<<<256, 512, 0, stream>>>(fc, Wfc2, yp);
  k_ln<<<32, 256, 0, stream>>>(yp, bfc2, g2, b2, out);
}

// Round 5
// 150.746 us; speedup vs baseline: 1.2727x; 1.0131x over previous
//
#include <hip/hip_runtime.h>
#include <hip/hip_bf16.h>

// Problem: OptimAttn  B=32, SIZE=2048, OUT=2048 — ALL I/O float32.
// valued[b,i] = sum_j exp(q_i k_j - M) v_j / Z_b,  Z_b = sum_{i,j} exp(q_i k_j - M)
// M = max of 4 corner products of (qmin,qmax)x(kmin,kmax)  (exact global max).
// Matmuls: truncation-split bf16 MFMA (f32 = hi + lo; 3 MFMAs) -> ~2^-16 rel error.
// Round 5: k_attn i-tiled x2 per lane with v_pk_fma_f32 packed math (7 cyc/exp vs 11);
// k_fc split-K x4 for dispatch granularity.

#define S 2048
#define BATCH 32

typedef __attribute__((ext_vector_type(8))) short short8;   // 8 x bf16 (MFMA A/B frag)
typedef __attribute__((ext_vector_type(4))) float f32x4;    // MFMA C/D frag
typedef __attribute__((ext_vector_type(2))) float f32x2;    // packed fp32 (v_pk_*_f32)

#if __has_builtin(__builtin_elementwise_fma)
__device__ __forceinline__ f32x2 pkfma(f32x2 a, f32x2 b, f32x2 c) {
  return __builtin_elementwise_fma(a, b, c);
}
#else
__device__ __forceinline__ f32x2 pkfma(f32x2 a, f32x2 b, f32x2 c) {
  f32x2 r; r.x = fmaf(a.x, b.x, c.x); r.y = fmaf(a.y, b.y, c.y); return r;
}
#endif

// Truncation-based f32 -> (hi,lo) bf16 split, ~4 VALU/elem.
__device__ __forceinline__ void cvt8t(const float* __restrict__ p, short8& hi, short8& lo) {
  const float4* p4 = (const float4*)p;
  float4 a = p4[0], b = p4[1];
  float v[8] = {a.x, a.y, a.z, a.w, b.x, b.y, b.z, b.w};
#pragma unroll
  for (int t = 0; t < 8; ++t) {
    union { float f; unsigned u; } x; x.f = v[t];
    hi[t] = (short)(x.u >> 16);
    union { unsigned u; float f; } h; h.u = x.u & 0xFFFF0000u;
    union { float f; unsigned u; } l; l.f = v[t] - h.f;
    lo[t] = (short)(l.u >> 16);
  }
}

// ---------------- K1: qkv partials = x @ W{q,k,v}.T over K-half ----------------
// grid: 768 = mi(3) x kh(2) x nblk(128).  wg=256: 4 waves x 256 K each.
__global__ __launch_bounds__(256) void k_qkv(
    const float* __restrict__ x,
    const float* __restrict__ Wq,
    const float* __restrict__ Wk,
    const float* __restrict__ Wv,
    float* __restrict__ qkvp) {
  int bid  = blockIdx.x;
  int mi   = bid >> 8;          // 0..2
  int kh   = (bid >> 7) & 1;    // K half
  int nblk = bid & 127;
  const float* W = (mi == 0) ? Wq : (mi == 1) ? Wk : Wv;
  float* out = qkvp + (size_t)kh * (3 * BATCH * S) + (size_t)mi * (BATCH * S);

  int tid  = threadIdx.x;
  int wave = tid >> 6;
  int lane = tid & 63;
  int lr   = lane & 15;
  int quad = lane >> 4;

  f32x4 acc0 = {0.f, 0.f, 0.f, 0.f};
  f32x4 acc1 = {0.f, 0.f, 0.f, 0.f};
  const float* wrow = W + (size_t)(nblk * 16 + lr) * S;
  const float* xr0  = x + (size_t)lr * S;
  const float* xr1  = x + (size_t)(lr + 16) * S;
  int kbase = kh * 1024 + wave * 256 + quad * 8;

#pragma unroll 2
  for (int ks = 0; ks < 8; ++ks) {
    int k0 = kbase + ks * 32;
    short8 bhi, blo, a0h, a0l, a1h, a1l;
    cvt8t(wrow + k0, bhi, blo);
    cvt8t(xr0 + k0, a0h, a0l);
    cvt8t(xr1 + k0, a1h, a1l);
    acc0 = __builtin_amdgcn_mfma_f32_16x16x32_bf16(a0h, bhi, acc0, 0, 0, 0);
    acc0 = __builtin_amdgcn_mfma_f32_16x16x32_bf16(a0l, bhi, acc0, 0, 0, 0);
    acc0 = __builtin_amdgcn_mfma_f32_16x16x32_bf16(a0h, blo, acc0, 0, 0, 0);
    acc1 = __builtin_amdgcn_mfma_f32_16x16x32_bf16(a1h, bhi, acc1, 0, 0, 0);
    acc1 = __builtin_amdgcn_mfma_f32_16x16x32_bf16(a1l, bhi, acc1, 0, 0, 0);
    acc1 = __builtin_amdgcn_mfma_f32_16x16x32_bf16(a1h, blo, acc1, 0, 0, 0);
  }

  __shared__ float red[4][64][8];
#pragma unroll
  for (int r = 0; r < 4; ++r) {
    red[wave][lane][r]     = acc0[r];
    red[wave][lane][4 + r] = acc1[r];
  }
  __syncthreads();
  if (tid < 64) {
    int lq = tid >> 4, lc = tid & 15;
    int n = nblk * 16 + lc;
#pragma unroll
    for (int r = 0; r < 8; ++r) {
      float s = red[0][tid][r] + red[1][tid][r] + red[2][tid][r] + red[3][tid][r];
      int m = (r < 4) ? (lq * 4 + r) : (16 + lq * 4 + (r - 4));
      out[m * S + n] = s;
    }
  }
}

// ---------------- K2: attention numerator T[b,i] and partial sums Spart ----------------
// grid: 512 = 32 batches * 16 i-blocks of 128.  wg=512: lane owns i and i+64 (packed),
// wave = j-chunk of 256.  Inner loop: v_pk_fma args, 2x v_exp, v_pk_add / v_pk_fma acc.
__global__ __launch_bounds__(512) void k_attn(
    const float* __restrict__ qkvp, float* __restrict__ Tout, float* __restrict__ Spart) {
  int b    = blockIdx.x >> 4;
  int iblk = blockIdx.x & 15;
  const float* qA = qkvp + (size_t)b * S;
  const float* kA = qA + BATCH * S;
  const float* vA = qA + 2 * BATCH * S;
  const float* qB = qA + 3 * BATCH * S;
  const float* kB = kA + 3 * BATCH * S;
  const float* vB = vA + 3 * BATCH * S;

  __shared__ __align__(16) float2 kv[S];
  __shared__ float qsh[128];
  __shared__ float redmx[8][4];
  __shared__ f32x2 redT[512];
  __shared__ float redS[512];
  __shared__ float Msh;

  int tid = threadIdx.x;
  float qmx = -1e30f, qmn = 1e30f, kmx = -1e30f, kmn = 1e30f;
  for (int idx = tid; idx < S; idx += 512) {
    float kk = kA[idx] + kB[idx];
    float vv = vA[idx] + vB[idx];
    float qq = qA[idx] + qB[idx];
    kv[idx] = make_float2(kk, vv);
    if ((idx >> 7) == iblk) qsh[idx & 127] = qq;
    qmx = fmaxf(qmx, qq); qmn = fminf(qmn, qq);
    kmx = fmaxf(kmx, kk); kmn = fminf(kmn, kk);
  }
  for (int off = 32; off; off >>= 1) {
    qmx = fmaxf(qmx, __shfl_xor(qmx, off));
    qmn = fminf(qmn, __shfl_xor(qmn, off));
    kmx = fmaxf(kmx, __shfl_xor(kmx, off));
    kmn = fminf(kmn, __shfl_xor(kmn, off));
  }
  int wave = tid >> 6, lane = tid & 63;
  if (lane == 0) {
    redmx[wave][0] = qmx; redmx[wave][1] = qmn;
    redmx[wave][2] = kmx; redmx[wave][3] = kmn;
  }
  __syncthreads();
  if (tid == 0) {
    float a = redmx[0][0], bn = redmx[0][1], c = redmx[0][2], d = redmx[0][3];
    for (int w = 1; w < 8; ++w) {
      a = fmaxf(a, redmx[w][0]); bn = fminf(bn, redmx[w][1]);
      c = fmaxf(c, redmx[w][2]); d = fminf(d, redmx[w][3]);
    }
    Msh = fmaxf(fmaxf(a * c, a * d), fmaxf(bn * c, bn * d));
  }
  __syncthreads();
  float M = Msh;

  const float LOG2E = 1.4426950408889634f;
  f32x2 aa = {qsh[lane] * LOG2E, qsh[lane + 64] * LOG2E};
  float ccs = -M * LOG2E;
  f32x2 cc = {ccs, ccs};
  f32x2 Sp = {0.f, 0.f}, Sq = {0.f, 0.f};
  f32x2 Tp = {0.f, 0.f}, Tq = {0.f, 0.f};
  int j0 = wave * 256;
#pragma unroll 4
  for (int j = j0; j < j0 + 256; j += 2) {
    float4 p = *(const float4*)&kv[j];   // (k0,v0,k1,v1) wave-uniform -> broadcast
    f32x2 kk0 = {p.x, p.x}, vv0 = {p.y, p.y};
    f32x2 kk1 = {p.z, p.z}, vv1 = {p.w, p.w};
    f32x2 a0 = pkfma(aa, kk0, cc);
    f32x2 a1 = pkfma(aa, kk1, cc);
    f32x2 e0 = {__builtin_amdgcn_exp2f(a0.x), __builtin_amdgcn_exp2f(a0.y)};
    f32x2 e1 = {__builtin_amdgcn_exp2f(a1.x), __builtin_amdgcn_exp2f(a1.y)};
    Sp += e0;
    Sq += e1;
    Tp = pkfma(e0, vv0, Tp);
    Tq = pkfma(e1, vv1, Tq);
  }
  redT[tid] = Tp + Tq;
  redS[tid] = Sp.x + Sp.y + Sq.x + Sq.y;
  __syncthreads();
  if (tid < 128) {
    int l = tid & 63, hi = tid >> 6;
    float Tf = 0.f;
#pragma unroll
    for (int w = 0; w < 8; ++w) {
      f32x2 t = redT[w * 64 + l];
      Tf += hi ? t.y : t.x;
    }
    Tout[b * S + iblk * 128 + tid] = Tf;
  }
  if (tid < 64) {
    float Sf = 0.f;
#pragma unroll
    for (int w = 0; w < 8; ++w) Sf += redS[w * 64 + tid];
    for (int off = 32; off; off >>= 1) Sf += __shfl_xor(Sf, off);
    if (tid == 0) Spart[b * 16 + iblk] = Sf;
  }
}

// ---------------- K2b: fc = activation(T/Z)  (fp32); Z from 16 partials ----------------
__global__ __launch_bounds__(256) void k_act(
    const float* __restrict__ Tin, const float* __restrict__ Spart,
    const float* __restrict__ p2, float* __restrict__ fc) {
  int tid = threadIdx.x;
  int gid = blockIdx.x * 256 + tid;   // 0..65535
  int b = gid >> 11;                  // uniform per block (2048 per b, 8 blocks/b)
  __shared__ float Zsh;
  if (tid < 64) {
    float zv = (tid < 16) ? Spart[b * 16 + tid] : 0.f;
    for (int off = 32; off; off >>= 1) zv += __shfl_xor(zv, off);
    if (tid == 0) Zsh = zv;
  }
  __syncthreads();
  float Z = Zsh;

  const float LOG2E = 1.4426950408889634f;
  float p[5];
  float mx = -1e30f;
#pragma unroll
  for (int t = 0; t < 5; ++t) { p[t] = p2[t]; mx = fmaxf(mx, p[t]); }
  float se = 0.f;
#pragma unroll
  for (int t = 0; t < 5; ++t) { p[t] = __builtin_amdgcn_exp2f((p[t] - mx) * LOG2E); se += p[t]; }
  float inv = 1.f / se;
  float val = Tin[gid] / Z;
  float sig = __builtin_amdgcn_rcpf(1.f + __builtin_amdgcn_exp2f(-val * LOG2E));
  float sn  = __builtin_amdgcn_sinf(val * 0.15915494309189535f);  // v_sin takes revolutions
  fc[gid] = sig * val * (p[0] * inv) + sn * (p[1] * inv) + val * (p[2] * inv);
}

// ---------------- K3: y partials = fc @ Wfc2.T over K-quarter (no bias) ----------------
// grid: 512 = kq(4) x nblk(128).  wg=256: 4 waves x 128 K each.
__global__ __launch_bounds__(256) void k_fc(
    const float* __restrict__ fc,
    const float* __restrict__ W,
    float* __restrict__ yp) {
  int bid  = blockIdx.x;
  int kq   = bid >> 7;          // 0..3
  int nblk = bid & 127;
  int tid  = threadIdx.x;
  int wave = tid >> 6;
  int lane = tid & 63;
  int lr   = lane & 15;
  int quad = lane >> 4;

  f32x4 acc0 = {0.f, 0.f, 0.f, 0.f};
  f32x4 acc1 = {0.f, 0.f, 0.f, 0.f};
  const float* wrow = W + (size_t)(nblk * 16 + lr) * S;
  const float* xr0  = fc + (size_t)lr * S;
  const float* xr1  = fc + (size_t)(lr + 16) * S;
  int kbase = kq * 512 + wave * 128 + quad * 8;

#pragma unroll
  for (int ks = 0; ks < 4; ++ks) {
    int k0 = kbase + ks * 32;
    short8 bhi, blo, a0h, a0l, a1h, a1l;
    cvt8t(wrow + k0, bhi, blo);
    cvt8t(xr0 + k0, a0h, a0l);
    cvt8t(xr1 + k0, a1h, a1l);
    acc0 = __builtin_amdgcn_mfma_f32_16x16x32_bf16(a0h, bhi, acc0, 0, 0, 0);
    acc0 = __builtin_amdgcn_mfma_f32_16x16x32_bf16(a0l, bhi, acc0, 0, 0, 0);
    acc0 = __builtin_amdgcn_mfma_f32_16x16x32_bf16(a0h, blo, acc0, 0, 0, 0);
    acc1 = __builtin_amdgcn_mfma_f32_16x16x32_bf16(a1h, bhi, acc1, 0, 0, 0);
    acc1 = __builtin_amdgcn_mfma_f32_16x16x32_bf16(a1l, bhi, acc1, 0, 0, 0);
    acc1 = __builtin_amdgcn_mfma_f32_16x16x32_bf16(a1h, blo, acc1, 0, 0, 0);
  }

  __shared__ float red[4][64][8];
#pragma unroll
  for (int r = 0; r < 4; ++r) {
    red[wave][lane][r]     = acc0[r];
    red[wave][lane][4 + r] = acc1[r];
  }
  __syncthreads();
  if (tid < 64) {
    int lq = tid >> 4, lc = tid & 15;
    int n = nblk * 16 + lc;
#pragma unroll
    for (int r = 0; r < 8; ++r) {
      float s = red[0][tid][r] + red[1][tid][r] + red[2][tid][r] + red[3][tid][r];
      int m = (r < 4) ? (lq * 4 + r) : (16 + lq * 4 + (r - 4));
      yp[(size_t)kq * BATCH * S + m * S + n] = s;
    }
  }
}

// ---------------- K4: layernorm(y0+y1+y2+y3+bias) -> fp32 output ----------------
__global__ __launch_bounds__(256) void k_ln(
    const float* __restrict__ yp, const float* __restrict__ bias,
    const float* __restrict__ g, const float* __restrict__ bb,
    float* __restrict__ out) {
  int b = blockIdx.x;
  const float* r0 = yp + (size_t)b * S;
  const float* r1 = r0 + BATCH * S;
  const float* r2 = r1 + BATCH * S;
  const float* r3 = r2 + BATCH * S;
  float t8[8];
  float s = 0.f, s2 = 0.f;
#pragma unroll
  for (int it = 0; it < 8; ++it) {
    int i = threadIdx.x + it * 256;
    float t = (r0[i] + r1[i]) + (r2[i] + r3[i]) + bias[i];
    t8[it] = t;
    s += t; s2 += t * t;
  }
  for (int off = 32; off; off >>= 1) {
    s  += __shfl_xor(s, off);
    s2 += __shfl_xor(s2, off);
  }
  __shared__ float rs[4], rs2[4];
  __shared__ float mu_s, r_s;
  int wave = threadIdx.x >> 6, lane = threadIdx.x & 63;
  if (lane == 0) { rs[wave] = s; rs2[wave] = s2; }
  __syncthreads();
  if (threadIdx.x == 0) {
    float S1 = rs[0] + rs[1] + rs[2] + rs[3];
    float S2 = rs2[0] + rs2[1] + rs2[2] + rs2[3];
    float mu = S1 / (float)S;
    float var = S2 / (float)S - mu * mu;
    mu_s = mu;
    r_s = rsqrtf(var + 1e-5f);
  }
  __syncthreads();
  float mu = mu_s, r = r_s;
#pragma unroll
  for (int it = 0; it < 8; ++it) {
    int i = threadIdx.x + it * 256;
    out[b * S + i] = (t8[it] - mu) * r * g[i] + bb[i];
  }
}

extern "C" void kernel_launch(void* const* d_in, const int* in_sizes, int n_in,
                              void* d_out, int out_size, void* d_ws, size_t ws_size,
                              hipStream_t stream) {
  (void)in_sizes; (void)n_in; (void)out_size; (void)ws_size;
  const float* x    = (const float*)d_in[0];
  const float* Wq   = (const float*)d_in[1];
  const float* Wk   = (const float*)d_in[2];
  const float* Wv   = (const float*)d_in[3];
  const float* p2   = (const float*)d_in[4];
  const float* Wfc2 = (const float*)d_in[5];
  const float* bfc2 = (const float*)d_in[6];
  const float* g2   = (const float*)d_in[7];
  const float* b2   = (const float*)d_in[8];
  float* out = (float*)d_out;

  float* qkvp  = (float*)d_ws;                    // 2 * 3*32*2048 f32
  float* T     = qkvp + 2 * 3 * BATCH * S;        // 32*2048 f32
  float* Spart = T + BATCH * S;                   // 32*16 f32
  float* fc    = Spart + BATCH * 16;              // 32*2048 f32
  float* yp    = fc + BATCH * S;                  // 4 * 32*2048 f32

  k_qkv<<<768, 256, 0, stream>>>(x, Wq, Wk, Wv, qkvp);
  k_attn<<<512, 512, 0, stream>>>(qkvp, T, Spart);
  k_act<<<256, 256, 0, stream>>>(T, Spart, p2, fc);
  k_fc<<<512, 256, 0, stream>>>(fc, Wfc2, yp);
  k_ln<<<32, 256, 0, stream>>>(yp, bfc2, g2, b2, out);
}